// Round 1
// baseline (1259.487 us; speedup 1.0000x reference)
//
#include <hip/hip_runtime.h>
#include <hip/hip_bf16.h>

#define BT 65536
#define DD 512
#define HH 512
#define NE 32
#define CAP 5120
#define BM 64
#define NRB 80   /* CAP/BM */

typedef float  f32x4  __attribute__((ext_vector_type(4)));
typedef short  bf16x8 __attribute__((ext_vector_type(8)));

__device__ __forceinline__ unsigned short f2bf(float f){
    unsigned int u = __builtin_bit_cast(unsigned int, f);
    unsigned int r = (u + 0x7fffu + ((u >> 16) & 1u)) >> 16;
    return (unsigned short)r;
}

// ---------------- weight transpose + bf16 convert ----------------
// W[e][k][n] fp32  ->  WT[e][n][k] bf16
__global__ __launch_bounds__(256) void k_wconv(
    const float* __restrict__ W1, const float* __restrict__ W2,
    unsigned short* __restrict__ W1T, unsigned short* __restrict__ W2T)
{
    int bid = blockIdx.x;
    const float* src = W1; unsigned short* dst = W1T;
    if (bid >= 2048){ src = W2; dst = W2T; bid -= 2048; }
    int e    = bid >> 6;
    int trow = (bid >> 3) & 7;   // k-tile
    int tcol = bid & 7;          // n-tile
    __shared__ float tile[64][65];
    const float* base = src + ((size_t)e << 18);
    int t = threadIdx.x;
    #pragma unroll
    for (int i = 0; i < 16; i++){
        int idx = i*256 + t;
        int k = idx >> 6, n = idx & 63;
        tile[k][n] = base[(size_t)(trow*64 + k)*512 + tcol*64 + n];
    }
    __syncthreads();
    unsigned short* ob = dst + ((size_t)e << 18);
    #pragma unroll
    for (int i = 0; i < 16; i++){
        int idx = i*256 + t;
        int n = idx >> 6, k = idx & 63;
        ob[(size_t)(tcol*64 + n)*512 + trow*64 + k] = f2bf(tile[k][n]);
    }
}

// ---------------- gating: fp64 logits, top-2, dispatch ----------------
__global__ __launch_bounds__(256) void k_gate(
    const float* __restrict__ x, const float* __restrict__ Wg,
    float* __restrict__ y, int* __restrict__ counts,
    int* __restrict__ toks, float* __restrict__ wts)
{
    __shared__ float xs[4][512];
    int lane = threadIdx.x & 63, wv = threadIdx.x >> 6;
    int t = blockIdx.x * 4 + wv;
    const float4* xg = (const float4*)(x + (size_t)t * DD);
    float4* xsv = (float4*)xs[wv];
    xsv[lane]      = xg[lane];
    xsv[64 + lane] = xg[64 + lane];
    __syncthreads();

    int e = lane & 31, half = lane >> 5;
    const float* xrow = xs[wv] + half*256;
    const float* wgb  = Wg + (size_t)(half*256)*NE + e;
    double a0=0.0, a1=0.0, a2=0.0, a3=0.0;
    #pragma unroll 4
    for (int d = 0; d < 256; d += 4){
        a0 = fma((double)xrow[d+0], (double)wgb[(d+0)*NE], a0);
        a1 = fma((double)xrow[d+1], (double)wgb[(d+1)*NE], a1);
        a2 = fma((double)xrow[d+2], (double)wgb[(d+2)*NE], a2);
        a3 = fma((double)xrow[d+3], (double)wgb[(d+3)*NE], a3);
    }
    double acc = (a0 + a1) + (a2 + a3);
    acc += __shfl_xor(acc, 32, 64);   // full logit for expert e on all lanes

    // top-1 (ties -> lowest index, matching lax.top_k)
    double v1 = acc; int i1 = e;
    #pragma unroll
    for (int m = 1; m < 32; m <<= 1){
        double ov = __shfl_xor(v1, m, 64);
        int    oi = __shfl_xor(i1, m, 64);
        if (ov > v1 || (ov == v1 && oi < i1)){ v1 = ov; i1 = oi; }
    }
    // top-2
    double v2 = (e == i1) ? -1.0e300 : acc; int i2 = (e == i1) ? 0x7fffffff : e;
    #pragma unroll
    for (int m = 1; m < 32; m <<= 1){
        double ov = __shfl_xor(v2, m, 64);
        int    oi = __shfl_xor(i2, m, 64);
        if (ov > v2 || (ov == v2 && oi < i2)){ v2 = ov; i2 = oi; }
    }
    double ex  = exp(v2 - v1);
    double inv = 1.0 / (1.0 + ex);
    float w1 = (float)inv;
    float w2 = (float)(ex * inv);

    int s1 = 0, s2 = 0;
    if (lane == 0)  s1 = atomicAdd(&counts[i1], 1);
    if (lane == 32) s2 = atomicAdd(&counts[i2], 1);
    s1 = __shfl(s1, 0, 64);
    s2 = __shfl(s2, 32, 64);
    bool k1 = s1 < CAP, k2 = s2 < CAP;
    if (lane == 0 && k1){ toks[i1*CAP + s1] = t; wts[i1*CAP + s1] = w1; }
    if (lane == 32 && k2){ toks[i2*CAP + s2] = t; wts[i2*CAP + s2] = w2; }

    float4* yv = (float4*)(y + (size_t)t * DD);
    if (k1 | k2){
        float4 z4; z4.x = 0.f; z4.y = 0.f; z4.z = 0.f; z4.w = 0.f;
        yv[lane] = z4; yv[64 + lane] = z4;
    } else {                       // both dropped: passthrough (statistically never)
        yv[lane] = xg[lane]; yv[64 + lane] = xg[64 + lane];
    }
}

// ---------------- fused expert FFN: relu(Xg@W1+b1)@W2+b2, scatter-add ----------------
__global__ __launch_bounds__(512, 2) void k_ffn(
    const float* __restrict__ x,
    const unsigned short* __restrict__ W1T,
    const unsigned short* __restrict__ W2T,
    const float* __restrict__ b1, const float* __restrict__ b2,
    const int* __restrict__ counts,
    const int* __restrict__ toks, const float* __restrict__ wts,
    float* __restrict__ y)
{
    __shared__ unsigned char AH[64 * 1024];      // 64 rows x 512 bf16, 16B-chunk XOR swizzle (r&7)
    __shared__ unsigned char Bb[2][32 * 1024];   // 512 rows x 32 bf16 (64B rows), chunk XOR ((n>>1)&3)

    int e  = blockIdx.x / NRB;
    int rb = blockIdx.x % NRB;
    int cnt = counts[e]; if (cnt > CAP) cnt = CAP;
    int r0 = rb * BM;
    if (r0 >= cnt) return;

    int tid  = threadIdx.x;
    int lane = tid & 63;
    int wid  = tid >> 6;
    int wm = wid >> 2;       // 0..1 : 32-row half
    int wn = wid & 3;        // 0..3 : 128-col slice

    // ---- stage A: gather x rows, convert to bf16, swizzled ----
    {
        int row = tid >> 3, seg = tid & 7;
        int gr  = r0 + row;
        char* rowb = (char*)AH + row * 1024;
        int rsw = (row & 7) << 4;
        if (gr < cnt){
            int tk = toks[e*CAP + gr];
            const float4* src = (const float4*)(x + (size_t)tk*DD + seg*64);
            #pragma unroll
            for (int j = 0; j < 8; j++){
                float4 f0 = src[2*j], f1 = src[2*j+1];
                bf16x8 p;
                p[0]=(short)f2bf(f0.x); p[1]=(short)f2bf(f0.y); p[2]=(short)f2bf(f0.z); p[3]=(short)f2bf(f0.w);
                p[4]=(short)f2bf(f1.x); p[5]=(short)f2bf(f1.y); p[6]=(short)f2bf(f1.z); p[7]=(short)f2bf(f1.w);
                int chunk = seg*8 + j;
                *(bf16x8*)(rowb + ((chunk << 4) ^ rsw)) = p;
            }
        } else {
            bf16x8 zz = (bf16x8)0;
            #pragma unroll
            for (int j = 0; j < 8; j++){
                int chunk = seg*8 + j;
                *(bf16x8*)(rowb + ((chunk << 4) ^ rsw)) = zz;
            }
        }
    }

    float bias1[8], bias2[8];
    #pragma unroll
    for (int nf = 0; nf < 8; nf++){
        int col = wn*128 + nf*16 + (lane & 15);
        bias1[nf] = b1[e*HH + col];
        bias2[nf] = b2[e*DD + col];
    }

    f32x4 acc[2][8];
    #pragma unroll
    for (int mf = 0; mf < 2; mf++)
        #pragma unroll
        for (int nf = 0; nf < 8; nf++)
            acc[mf][nf] = (f32x4)0.f;

    // B chunk c: layer = c>>4, kk = (c&15)*32; thread stages 4 x 16B
    bf16x8 stg[4];
    {   // prologue chunk 0
        const unsigned short* Wb = W1T + ((size_t)e << 18);
        #pragma unroll
        for (int j = 0; j < 4; j++){
            int m = j*512 + tid; int n = m >> 2, cd = m & 3;
            stg[j] = *(const bf16x8*)(Wb + (size_t)n*512 + cd*8);
        }
        char* lb = (char*)Bb[0];
        #pragma unroll
        for (int j = 0; j < 4; j++){
            int m = j*512 + tid; int n = m >> 2, cd = m & 3;
            *(bf16x8*)(lb + n*64 + ((cd ^ ((n >> 1) & 3)) << 4)) = stg[j];
        }
    }
    __syncthreads();

    int cur = 0;
    #pragma unroll 1
    for (int c = 0; c < 32; c++){
        if (c < 31){
            int cn = c + 1;
            const unsigned short* Wb = ((cn < 16) ? W1T : W2T) + ((size_t)e << 18) + (cn & 15)*32;
            #pragma unroll
            for (int j = 0; j < 4; j++){
                int m = j*512 + tid; int n = m >> 2, cd = m & 3;
                stg[j] = *(const bf16x8*)(Wb + (size_t)n*512 + cd*8);
            }
        }
        // compute chunk c
        {
            bf16x8 a[2], b[8];
            int kchunk0 = ((c & 15) << 2) + (lane >> 4);
            #pragma unroll
            for (int mf = 0; mf < 2; mf++){
                int r = wm*32 + mf*16 + (lane & 15);
                a[mf] = *(const bf16x8*)((char*)AH + r*1024 + ((kchunk0 ^ (r & 7)) << 4));
            }
            int cd = lane >> 4;
            #pragma unroll
            for (int nf = 0; nf < 8; nf++){
                int n = wn*128 + nf*16 + (lane & 15);
                b[nf] = *(const bf16x8*)((char*)Bb[cur] + n*64 + ((cd ^ ((n >> 1) & 3)) << 4));
            }
            #pragma unroll
            for (int mf = 0; mf < 2; mf++)
                #pragma unroll
                for (int nf = 0; nf < 8; nf++)
                    acc[mf][nf] = __builtin_amdgcn_mfma_f32_16x16x32_bf16(a[mf], b[nf], acc[mf][nf], 0, 0, 0);
        }

        if (c == 15){
            __syncthreads();   // all waves done reading X from AH
            #pragma unroll
            for (int mf = 0; mf < 2; mf++){
                #pragma unroll
                for (int nf = 0; nf < 8; nf++){
                    int col = wn*128 + nf*16 + (lane & 15);
                    #pragma unroll
                    for (int i = 0; i < 4; i++){
                        int r = wm*32 + mf*16 + ((lane >> 4) << 2) + i;
                        float h = acc[mf][nf][i] + bias1[nf];
                        h = h > 0.f ? h : 0.f;
                        char* p = (char*)AH + r*1024 + ((((col >> 3) ^ (r & 7)) << 4)) + (col & 7)*2;
                        *(unsigned short*)p = f2bf(h);
                        acc[mf][nf][i] = 0.f;
                    }
                }
            }
        }

        if (c < 31){
            char* lb = (char*)Bb[cur ^ 1];
            #pragma unroll
            for (int j = 0; j < 4; j++){
                int m = j*512 + tid; int n = m >> 2, cd = m & 3;
                *(bf16x8*)(lb + n*64 + ((cd ^ ((n >> 1) & 3)) << 4)) = stg[j];
            }
        }
        __syncthreads();
        cur ^= 1;
    }

    // epilogue: o = acc + b2; y[tok] += w * o
    #pragma unroll
    for (int mf = 0; mf < 2; mf++){
        #pragma unroll
        for (int i = 0; i < 4; i++){
            int rl = wm*32 + mf*16 + ((lane >> 4) << 2) + i;
            int gr = r0 + rl;
            if (gr < cnt){
                int   tk = toks[e*CAP + gr];
                float w  = wts[e*CAP + gr];
                float* yr = y + (size_t)tk * DD;
                #pragma unroll
                for (int nf = 0; nf < 8; nf++){
                    int col = wn*128 + nf*16 + (lane & 15);
                    atomicAdd(yr + col, w * (acc[mf][nf][i] + bias2[nf]));
                }
            }
        }
    }
}

extern "C" void kernel_launch(void* const* d_in, const int* in_sizes, int n_in,
                              void* d_out, int out_size, void* d_ws, size_t ws_size,
                              hipStream_t stream)
{
    const float* x  = (const float*)d_in[0];
    const float* Wg = (const float*)d_in[1];
    const float* W1 = (const float*)d_in[2];
    const float* b1 = (const float*)d_in[3];
    const float* W2 = (const float*)d_in[4];
    const float* b2 = (const float*)d_in[5];
    float* y = (float*)d_out;

    char* ws = (char*)d_ws;
    unsigned short* W1T = (unsigned short*)(ws);
    unsigned short* W2T = (unsigned short*)(ws + 16777216);
    int*   counts = (int*)  (ws + 33554432);
    int*   toks   = (int*)  (ws + 33554432 + 256);
    float* wts    = (float*)(ws + 33554432 + 256 + 655360);

    hipMemsetAsync(counts, 0, 256, stream);
    hipLaunchKernelGGL(k_wconv, dim3(4096), dim3(256), 0, stream, W1, W2, W1T, W2T);
    hipLaunchKernelGGL(k_gate,  dim3(BT/4), dim3(256), 0, stream, x, Wg, y, counts, toks, wts);
    hipLaunchKernelGGL(k_ffn,   dim3(NE*NRB), dim3(512), 0, stream, x, W1T, W2T, b1, b2, counts, toks, wts, y);
}